// Round 5
// baseline (537.751 us; speedup 1.0000x reference)
//
#include <hip/hip_runtime.h>

// Permutohedral lattice filter, PD=3, VD=5 (4 channels + homogeneous 1)
// Dense-grid lattice addressing: keys (k0,k1,k2) all share residue mod 4 and
// (for the fixed feature ranges coords/5) fit K0=k0+16, K1=k1+48, K2=k2+88,
// each in [0,128). Dense index = (K2>>2,K1>>2,K0>>2,K0&3) -> 2^17 cells.

#define DD    64
#define HHH   128
#define WWW   128
#define NPTS  (DD * HHH * WWW)          // 1048576
#define LATN  (1 << 17)                 // dense lattice cells
#define LATF  (LATN * 5)                // floats per lattice buffer
#define SH_BITS 10
#define SHSZ (1 << SH_BITS)             // 1024-entry per-block LDS hash

__device__ __forceinline__ int encK(int K0, int K1, int K2) {
    return ((K2 >> 2) << 12) | ((K1 >> 2) << 7) | ((K0 >> 2) << 2) | (K0 & 3);
}

// Full per-point geometry: elevate, round, rank, barycentric, 4 dense keys.
__device__ __forceinline__ void pl_geom(int z, int y, int x,
                                        const float* __restrict__ vg,
                                        const float* __restrict__ sg,
                                        int* didx, float* bout) {
    // features = [zz, yy, xx]; v_gamma[1] pairs with x, v_gamma[2] with y
    float f0 = vg[0] * (float)z / sg[0];
    float f1 = vg[2] * (float)y / sg[2];
    float f2 = vg[1] * (float)x / sg[1];

    const float m00 = (float)2.3094010767585034;   //  4/sqrt(3)
    const float m01 = (float)1.3333333333333333;   //  4/3
    const float m02 = (float)0.9428090415820634;   //  2*sqrt(2)/3
    const float m21 = (float)-2.6666666666666665;  // -2*(4/3)
    const float m32 = (float)-2.8284271247461903;  // -3*(2*sqrt(2)/3)

    float e[4];
    e[0] =  m00 * f0 + m01 * f1 + m02 * f2;
    e[1] = -m00 * f0 + m01 * f1 + m02 * f2;
    e[2] =  m21 * f1 + m02 * f2;
    e[3] =  m32 * f2;

    float rem0[4];
    int sumr = 0;
    #pragma unroll
    for (int i = 0; i < 4; ++i) {
        float v = e[i] * 0.25f;
        float up = ceilf(v), dn = floorf(v);
        float rr = ((up - v) < (v - dn)) ? up : dn;
        rem0[i] = rr * 4.0f;
        sumr += (int)rem0[i];
    }
    sumr /= 4;   // exact: sum of multiples of 4

    float diff[4];
    #pragma unroll
    for (int i = 0; i < 4; ++i) diff[i] = e[i] - rem0[i];
    int rank[4] = {0, 0, 0, 0};
    #pragma unroll
    for (int i = 0; i < 4; ++i)
        #pragma unroll
        for (int j = i + 1; j < 4; ++j) {
            if (diff[i] < diff[j]) rank[i]++; else rank[j]++;
        }

    #pragma unroll
    for (int i = 0; i < 4; ++i) {
        rank[i] += sumr;
        if (rank[i] < 0)      { rank[i] += 4; rem0[i] += 4.0f; }
        else if (rank[i] > 3) { rank[i] -= 4; rem0[i] -= 4.0f; }
    }

    float b[5] = {0.f, 0.f, 0.f, 0.f, 0.f};
    #pragma unroll
    for (int i = 0; i < 4; ++i) {
        float t = (e[i] - rem0[i]) * 0.25f;
        b[3 - rank[i]] += t;
        b[4 - rank[i]] -= t;
    }
    b[0] += 1.0f + b[4];

    int k0 = (int)rem0[0], k1 = (int)rem0[1], k2 = (int)rem0[2];
    #pragma unroll
    for (int r = 0; r < 4; ++r) {
        int o0 = (rank[0] >= 4 - r) ? (r - 4) : r;
        int o1 = (rank[1] >= 4 - r) ? (r - 4) : r;
        int o2 = (rank[2] >= 4 - r) ? (r - 4) : r;
        int K0 = (k0 + o0 + 16) & 127;   // mask = crash-safety only; in-range
        int K1 = (k1 + o1 + 48) & 127;   // for the fixed input feature scales
        int K2 = (k2 + o2 + 88) & 127;
        didx[r] = encK(K0, K1, K2);
        bout[r] = b[r];
    }
}

// ---------------------------------------------------------------- splat
__device__ __forceinline__ void pl_emit(int key, const float* a,
                                        int* skey, float (*sacc)[5],
                                        float* __restrict__ latc,
                                        unsigned char* __restrict__ exists) {
    unsigned idx = ((unsigned)key * 2654435761u) >> (32 - SH_BITS);
    int probes = 0;
    bool inlds = true;
    for (;;) {
        int cur = skey[idx];
        if (cur == key) break;
        if (cur == -1) {
            cur = atomicCAS(&skey[idx], -1, key);
            if (cur == -1 || cur == key) break;
        }
        idx = (idx + 1) & (SHSZ - 1);
        if (++probes >= SHSZ) { inlds = false; break; }
    }
    if (inlds) {
        #pragma unroll
        for (int c = 0; c < 5; ++c) atomicAdd(&sacc[idx][c], a[c]);
    } else {                              // table full (shouldn't happen)
        float* L = latc + (size_t)key * 5;
        #pragma unroll
        for (int c = 0; c < 5; ++c) atomicAdd(L + c, a[c]);
        exists[key] = 1;
    }
}

// Block = 512 threads covering a 32x16x4 (x,y,z) tile; 4 consecutive x per
// thread with register run-merging (merge rate ~85%/px). Thread->x mapping is
// spread so consecutive lanes are 8 px apart: corner keys within a 16-lane
// LDS phase are distinct -> no same-address ds_add serialization. Flush goes
// to one of 4 lat copies (blockIdx&3) to divide global-atomic contention.
__global__ __launch_bounds__(512, 4)
void pl_splat(const float* __restrict__ vals, const float* __restrict__ vg,
              const float* __restrict__ sg, float* __restrict__ latc,
              unsigned char* __restrict__ exists) {
    __shared__ int   skey[SHSZ];          // 4 KB
    __shared__ float sacc[SHSZ][5];       // 20 KB
    for (int i = threadIdx.x; i < SHSZ; i += 512) {
        skey[i] = -1;
        #pragma unroll
        for (int c = 0; c < 5; ++c) sacc[i][c] = 0.f;
    }
    __syncthreads();

    float* mycopy = latc + (size_t)(blockIdx.x & 3) * LATF;

    // grid = (128/32) * (128/16) * (64/4) = 4*8*16 = 512 blocks
    int bt = blockIdx.x;
    int xs = threadIdx.x & 7;             // 8 x-slots of 4 px
    int ly = (threadIdx.x >> 3) & 15;
    int lz = threadIdx.x >> 7;
    int xsl = ((xs & 3) << 1) | (xs >> 2);   // spread: 0,2,4,6,1,3,5,7
    int x0 = ((bt & 3) << 5) + (xsl << 2);
    int y  = (((bt >> 2) & 7) << 4) + ly;
    int z  = ((bt >> 5) << 2) + lz;
    int n0 = (z << 14) + (y << 7) + x0;

    float4 q0 = *(const float4*)(vals + n0);
    float4 q1 = *(const float4*)(vals + NPTS + n0);
    float4 q2 = *(const float4*)(vals + 2 * NPTS + n0);
    float4 q3 = *(const float4*)(vals + 3 * NPTS + n0);
    float ch0[4] = {q0.x, q0.y, q0.z, q0.w};
    float ch1[4] = {q1.x, q1.y, q1.z, q1.w};
    float ch2[4] = {q2.x, q2.y, q2.z, q2.w};
    float ch3[4] = {q3.x, q3.y, q3.z, q3.w};

    int ckey[4];
    float acc[4][5];
    {
        int didx[4]; float b[4];
        pl_geom(z, y, x0, vg, sg, didx, b);
        #pragma unroll
        for (int r = 0; r < 4; ++r) {
            ckey[r] = didx[r];
            float w = b[r];
            acc[r][0] = w * ch0[0]; acc[r][1] = w * ch1[0];
            acc[r][2] = w * ch2[0]; acc[r][3] = w * ch3[0];
            acc[r][4] = w;
        }
    }
    #pragma unroll
    for (int p = 1; p < 4; ++p) {
        int didx[4]; float b[4];
        pl_geom(z, y, x0 + p, vg, sg, didx, b);
        #pragma unroll
        for (int r = 0; r < 4; ++r) {
            float w = b[r];
            if (didx[r] == ckey[r]) {
                acc[r][0] += w * ch0[p]; acc[r][1] += w * ch1[p];
                acc[r][2] += w * ch2[p]; acc[r][3] += w * ch3[p];
                acc[r][4] += w;
            } else {
                pl_emit(ckey[r], acc[r], skey, sacc, mycopy, exists);
                ckey[r] = didx[r];
                acc[r][0] = w * ch0[p]; acc[r][1] = w * ch1[p];
                acc[r][2] = w * ch2[p]; acc[r][3] = w * ch3[p];
                acc[r][4] = w;
            }
        }
    }
    #pragma unroll
    for (int r = 0; r < 4; ++r)
        pl_emit(ckey[r], acc[r], skey, sacc, mycopy, exists);

    __syncthreads();

    int rot = (blockIdx.x * 131) & (SHSZ - 1);   // decorrelate flush order
    for (int ii = threadIdx.x; ii < SHSZ; ii += 512) {
        int i = (ii + rot) & (SHSZ - 1);
        int key = skey[i];
        if (key < 0) continue;
        exists[key] = 1;
        float* L = mycopy + (size_t)key * 5;
        #pragma unroll
        for (int c = 0; c < 5; ++c) atomicAdd(L + c, sacc[i][c]);
    }
}

// ------------------------------------------------- fused blur x4 + slice
// 512 blocks x 256 threads = 131072 threads = LATN, 2 blocks/CU -> all
// co-resident; grid barrier via device-scope atomic counters (re-zeroed by
// the up-front memset on every launch/replay).
__device__ __forceinline__ void gbar(int* cnt, int nblk) {
    __syncthreads();
    __threadfence();
    if (threadIdx.x == 0) {
        __hip_atomic_fetch_add(cnt, 1, __ATOMIC_RELEASE, __HIP_MEMORY_SCOPE_AGENT);
        while (__hip_atomic_load(cnt, __ATOMIC_ACQUIRE, __HIP_MEMORY_SCOPE_AGENT) < nblk)
            __builtin_amdgcn_s_sleep(2);
    }
    __syncthreads();
    __threadfence();
}

__device__ __forceinline__ void nbr_add1(const float* __restrict__ in,
                                         int K0, int K1, int K2, float* a) {
    if (((unsigned)K0 < 128u) & ((unsigned)K1 < 128u) & ((unsigned)K2 < 128u)) {
        const float* L = in + (size_t)encK(K0, K1, K2) * 5;
        #pragma unroll
        for (int c = 0; c < 5; ++c) a[c] += 0.5f * L[c];
    }
}
__device__ __forceinline__ void nbr_add4(const float* __restrict__ in,
                                         int K0, int K1, int K2, float* a) {
    if (((unsigned)K0 < 128u) & ((unsigned)K1 < 128u) & ((unsigned)K2 < 128u)) {
        size_t o = (size_t)encK(K0, K1, K2) * 5;
        #pragma unroll
        for (int c = 0; c < 5; ++c)
            a[c] += 0.5f * (in[o + c] + in[LATF + o + c] +
                            in[2 * LATF + o + c] + in[3 * LATF + o + c]);
    }
}

__global__ __launch_bounds__(256)
void pl_blur_slice(const float* __restrict__ latc, float* __restrict__ A,
                   float* __restrict__ B, const unsigned char* __restrict__ exists,
                   int* __restrict__ bar,
                   const float* __restrict__ vg, const float* __restrict__ sg,
                   float* __restrict__ out) {
    int didx = blockIdx.x * 256 + threadIdx.x;   // exactly LATN threads
    int r  = didx & 3;
    int K0 = (((didx >> 2)  & 31) << 2) | r;
    int K1 = (((didx >> 7)  & 31) << 2) | r;
    int K2 = (((didx >> 12) & 31) << 2) | r;
    bool act = exists[didx] != 0;
    int nblk = gridDim.x;

    // pass 0: sum(4 copies) -> A, offsets (-3,1,1)
    if (act) {
        float a[5];
        size_t o = (size_t)didx * 5;
        #pragma unroll
        for (int c = 0; c < 5; ++c)
            a[c] = latc[o + c] + latc[LATF + o + c] +
                   latc[2 * LATF + o + c] + latc[3 * LATF + o + c];
        nbr_add4(latc, K0 - 3, K1 + 1, K2 + 1, a);
        nbr_add4(latc, K0 + 3, K1 - 1, K2 - 1, a);
        float* O = A + o;
        #pragma unroll
        for (int c = 0; c < 5; ++c) O[c] = a[c];
    }
    gbar(bar + 0, nblk);

    // pass 1: A -> B, offsets (1,-3,1)
    if (act) {
        float a[5];
        const float* S = A + (size_t)didx * 5;
        #pragma unroll
        for (int c = 0; c < 5; ++c) a[c] = S[c];
        nbr_add1(A, K0 + 1, K1 - 3, K2 + 1, a);
        nbr_add1(A, K0 - 1, K1 + 3, K2 - 1, a);
        float* O = B + (size_t)didx * 5;
        #pragma unroll
        for (int c = 0; c < 5; ++c) O[c] = a[c];
    }
    gbar(bar + 1, nblk);

    // pass 2: B -> A, offsets (1,1,-3)
    if (act) {
        float a[5];
        const float* S = B + (size_t)didx * 5;
        #pragma unroll
        for (int c = 0; c < 5; ++c) a[c] = S[c];
        nbr_add1(B, K0 + 1, K1 + 1, K2 - 3, a);
        nbr_add1(B, K0 - 1, K1 - 1, K2 + 3, a);
        float* O = A + (size_t)didx * 5;
        #pragma unroll
        for (int c = 0; c < 5; ++c) O[c] = a[c];
    }
    gbar(bar + 2, nblk);

    // pass 3: A -> B, offsets (1,1,1)
    if (act) {
        float a[5];
        const float* S = A + (size_t)didx * 5;
        #pragma unroll
        for (int c = 0; c < 5; ++c) a[c] = S[c];
        nbr_add1(A, K0 + 1, K1 + 1, K2 + 1, a);
        nbr_add1(A, K0 - 1, K1 - 1, K2 - 1, a);
        float* O = B + (size_t)didx * 5;
        #pragma unroll
        for (int c = 0; c < 5; ++c) O[c] = a[c];
    }
    gbar(bar + 3, nblk);

    // slice from B, grid-stride over the 1M points
    for (int n = blockIdx.x * 256 + threadIdx.x; n < NPTS; n += LATN) {
        int z = n >> 14;
        int y = (n >> 7) & 127;
        int x = n & 127;
        int didx4[4]; float b[4];
        pl_geom(z, y, x, vg, sg, didx4, b);
        float a0 = 0.f, a1 = 0.f, a2 = 0.f, a3 = 0.f, a4 = 0.f;
        #pragma unroll
        for (int rr = 0; rr < 4; ++rr) {
            float w = b[rr];
            const float* L = B + (size_t)didx4[rr] * 5;
            a0 += w * L[0]; a1 += w * L[1]; a2 += w * L[2];
            a3 += w * L[3]; a4 += w * L[4];
        }
        const float alpha = (float)(1.0 / 1.125);
        float norm = alpha * a4 + (float)2.220446049250313e-16;
        float invn = 1.0f / norm;
        out[n]            = (alpha * a0) * invn;
        out[NPTS + n]     = (alpha * a1) * invn;
        out[2 * NPTS + n] = (alpha * a2) * invn;
        out[3 * NPTS + n] = (alpha * a3) * invn;
    }
}

// ---------------------------------------------------------------- launch
extern "C" void kernel_launch(void* const* d_in, const int* in_sizes, int n_in,
                              void* d_out, int out_size, void* d_ws, size_t ws_size,
                              hipStream_t stream) {
    const float* input = (const float*)d_in[0];   // (4,64,128,128)
    // d_in[1] = image: only its shape matters; unused.
    const float* vg = (const float*)d_in[2];
    const float* sg = (const float*)d_in[3];
    float* out = (float*)d_out;

    char* ws = (char*)d_ws;
    float* latc = (float*)ws;                        // 4 copies, contiguous
    float* A    = latc + (size_t)4 * LATF;
    float* B    = A + LATF;
    unsigned char* exists = (unsigned char*)(B + LATF);
    int* bar    = (int*)(exists + LATN);

    size_t zbytes = (size_t)6 * LATF * 4 + LATN + 64;   // copies+A+B+exists+bar
    hipMemsetAsync(ws, 0, zbytes, stream);

    pl_splat<<<512, dim3(512), 0, stream>>>(input, vg, sg, latc, exists);
    pl_blur_slice<<<LATN / 256, dim3(256), 0, stream>>>(latc, A, B, exists, bar,
                                                        vg, sg, out);
}

// Round 6
// 191.184 us; speedup vs baseline: 2.8127x; 2.8127x over previous
//
#include <hip/hip_runtime.h>

// Permutohedral lattice filter, PD=3, VD=5 (4 channels + homogeneous 1)
// Dense-grid lattice addressing: keys (k0,k1,k2) all share residue mod 4 and
// (for the fixed feature ranges coords/5) fit K0=k0+16, K1=k1+48, K2=k2+88,
// each in [0,128). Dense index = (K2>>2,K1>>2,K0>>2,K0&3) -> 2^17 cells.

#define DD    64
#define HHH   128
#define WWW   128
#define NPTS  (DD * HHH * WWW)          // 1048576
#define LATN  (1 << 17)                 // dense lattice cells
#define LATF  (LATN * 5)                // floats per lattice buffer
#define SH_BITS 10
#define SHSZ (1 << SH_BITS)             // 1024-entry per-block LDS hash
#define BLURBLK 64                      // blur grid (worklist ~12k cells)

__device__ __forceinline__ int encK(int K0, int K1, int K2) {
    return ((K2 >> 2) << 12) | ((K1 >> 2) << 7) | ((K0 >> 2) << 2) | (K0 & 3);
}

// Full per-point geometry: elevate, round, rank, barycentric, 4 dense keys.
__device__ __forceinline__ void pl_geom(int z, int y, int x,
                                        const float* __restrict__ vg,
                                        const float* __restrict__ sg,
                                        int* didx, float* bout) {
    // features = [zz, yy, xx]; v_gamma[1] pairs with x, v_gamma[2] with y
    float f0 = vg[0] * (float)z / sg[0];
    float f1 = vg[2] * (float)y / sg[2];
    float f2 = vg[1] * (float)x / sg[1];

    const float m00 = (float)2.3094010767585034;   //  4/sqrt(3)
    const float m01 = (float)1.3333333333333333;   //  4/3
    const float m02 = (float)0.9428090415820634;   //  2*sqrt(2)/3
    const float m21 = (float)-2.6666666666666665;  // -2*(4/3)
    const float m32 = (float)-2.8284271247461903;  // -3*(2*sqrt(2)/3)

    float e[4];
    e[0] =  m00 * f0 + m01 * f1 + m02 * f2;
    e[1] = -m00 * f0 + m01 * f1 + m02 * f2;
    e[2] =  m21 * f1 + m02 * f2;
    e[3] =  m32 * f2;

    float rem0[4];
    int sumr = 0;
    #pragma unroll
    for (int i = 0; i < 4; ++i) {
        float v = e[i] * 0.25f;
        float up = ceilf(v), dn = floorf(v);
        float rr = ((up - v) < (v - dn)) ? up : dn;
        rem0[i] = rr * 4.0f;
        sumr += (int)rem0[i];
    }
    sumr /= 4;   // exact: sum of multiples of 4

    float diff[4];
    #pragma unroll
    for (int i = 0; i < 4; ++i) diff[i] = e[i] - rem0[i];
    int rank[4] = {0, 0, 0, 0};
    #pragma unroll
    for (int i = 0; i < 4; ++i)
        #pragma unroll
        for (int j = i + 1; j < 4; ++j) {
            if (diff[i] < diff[j]) rank[i]++; else rank[j]++;
        }

    #pragma unroll
    for (int i = 0; i < 4; ++i) {
        rank[i] += sumr;
        if (rank[i] < 0)      { rank[i] += 4; rem0[i] += 4.0f; }
        else if (rank[i] > 3) { rank[i] -= 4; rem0[i] -= 4.0f; }
    }

    float b[5] = {0.f, 0.f, 0.f, 0.f, 0.f};
    #pragma unroll
    for (int i = 0; i < 4; ++i) {
        float t = (e[i] - rem0[i]) * 0.25f;
        b[3 - rank[i]] += t;
        b[4 - rank[i]] -= t;
    }
    b[0] += 1.0f + b[4];

    int k0 = (int)rem0[0], k1 = (int)rem0[1], k2 = (int)rem0[2];
    #pragma unroll
    for (int r = 0; r < 4; ++r) {
        int o0 = (rank[0] >= 4 - r) ? (r - 4) : r;
        int o1 = (rank[1] >= 4 - r) ? (r - 4) : r;
        int o2 = (rank[2] >= 4 - r) ? (r - 4) : r;
        int K0 = (k0 + o0 + 16) & 127;   // mask = crash-safety only; in-range
        int K1 = (k1 + o1 + 48) & 127;   // for the fixed input feature scales
        int K2 = (k2 + o2 + 88) & 127;
        didx[r] = encK(K0, K1, K2);
        bout[r] = b[r];
    }
}

// ---------------------------------------------------------------- splat
__device__ __forceinline__ void pl_claim(int key, unsigned int* __restrict__ exists,
                                         int* __restrict__ wcnt, int* __restrict__ wl) {
    if (atomicExch(&exists[key], 1u) == 0u) {
        int p = atomicAdd(wcnt, 1);
        wl[p] = key;
    }
}

__device__ __forceinline__ void pl_emit(int key, const float* a,
                                        int* skey, float (*sacc)[5],
                                        float* __restrict__ latc,
                                        unsigned int* __restrict__ exists,
                                        int* __restrict__ wcnt, int* __restrict__ wl) {
    unsigned idx = ((unsigned)key * 2654435761u) >> (32 - SH_BITS);
    int probes = 0;
    bool inlds = true;
    for (;;) {
        int cur = skey[idx];
        if (cur == key) break;
        if (cur == -1) {
            cur = atomicCAS(&skey[idx], -1, key);
            if (cur == -1 || cur == key) break;
        }
        idx = (idx + 1) & (SHSZ - 1);
        if (++probes >= SHSZ) { inlds = false; break; }
    }
    if (inlds) {
        #pragma unroll
        for (int c = 0; c < 5; ++c) atomicAdd(&sacc[idx][c], a[c]);
    } else {                              // table full (shouldn't happen)
        float* L = latc + (size_t)key * 5;
        #pragma unroll
        for (int c = 0; c < 5; ++c) atomicAdd(L + c, a[c]);
        pl_claim(key, exists, wcnt, wl);
    }
}

// Block = 512 threads covering a 32x16x4 (x,y,z) tile; 4 consecutive x per
// thread with register run-merging. Thread->x mapping spread so consecutive
// lanes are 8 px apart (no same-address ds_add serialization). Flush goes to
// one of 4 lat copies (blockIdx&3); first block to touch a key appends it to
// the compact active-cell worklist.
__global__ __launch_bounds__(512, 4)
void pl_splat(const float* __restrict__ vals, const float* __restrict__ vg,
              const float* __restrict__ sg, float* __restrict__ latc,
              unsigned int* __restrict__ exists,
              int* __restrict__ wcnt, int* __restrict__ wl) {
    __shared__ int   skey[SHSZ];          // 4 KB
    __shared__ float sacc[SHSZ][5];       // 20 KB
    for (int i = threadIdx.x; i < SHSZ; i += 512) {
        skey[i] = -1;
        #pragma unroll
        for (int c = 0; c < 5; ++c) sacc[i][c] = 0.f;
    }
    __syncthreads();

    float* mycopy = latc + (size_t)(blockIdx.x & 3) * LATF;

    // grid = (128/32) * (128/16) * (64/4) = 4*8*16 = 512 blocks
    int bt = blockIdx.x;
    int xs = threadIdx.x & 7;             // 8 x-slots of 4 px
    int ly = (threadIdx.x >> 3) & 15;
    int lz = threadIdx.x >> 7;
    int xsl = ((xs & 3) << 1) | (xs >> 2);   // spread: 0,2,4,6,1,3,5,7
    int x0 = ((bt & 3) << 5) + (xsl << 2);
    int y  = (((bt >> 2) & 7) << 4) + ly;
    int z  = ((bt >> 5) << 2) + lz;
    int n0 = (z << 14) + (y << 7) + x0;

    float4 q0 = *(const float4*)(vals + n0);
    float4 q1 = *(const float4*)(vals + NPTS + n0);
    float4 q2 = *(const float4*)(vals + 2 * NPTS + n0);
    float4 q3 = *(const float4*)(vals + 3 * NPTS + n0);
    float ch0[4] = {q0.x, q0.y, q0.z, q0.w};
    float ch1[4] = {q1.x, q1.y, q1.z, q1.w};
    float ch2[4] = {q2.x, q2.y, q2.z, q2.w};
    float ch3[4] = {q3.x, q3.y, q3.z, q3.w};

    int ckey[4];
    float acc[4][5];
    {
        int didx[4]; float b[4];
        pl_geom(z, y, x0, vg, sg, didx, b);
        #pragma unroll
        for (int r = 0; r < 4; ++r) {
            ckey[r] = didx[r];
            float w = b[r];
            acc[r][0] = w * ch0[0]; acc[r][1] = w * ch1[0];
            acc[r][2] = w * ch2[0]; acc[r][3] = w * ch3[0];
            acc[r][4] = w;
        }
    }
    #pragma unroll
    for (int p = 1; p < 4; ++p) {
        int didx[4]; float b[4];
        pl_geom(z, y, x0 + p, vg, sg, didx, b);
        #pragma unroll
        for (int r = 0; r < 4; ++r) {
            float w = b[r];
            if (didx[r] == ckey[r]) {
                acc[r][0] += w * ch0[p]; acc[r][1] += w * ch1[p];
                acc[r][2] += w * ch2[p]; acc[r][3] += w * ch3[p];
                acc[r][4] += w;
            } else {
                pl_emit(ckey[r], acc[r], skey, sacc, mycopy, exists, wcnt, wl);
                ckey[r] = didx[r];
                acc[r][0] = w * ch0[p]; acc[r][1] = w * ch1[p];
                acc[r][2] = w * ch2[p]; acc[r][3] = w * ch3[p];
                acc[r][4] = w;
            }
        }
    }
    #pragma unroll
    for (int r = 0; r < 4; ++r)
        pl_emit(ckey[r], acc[r], skey, sacc, mycopy, exists, wcnt, wl);

    __syncthreads();

    int rot = (blockIdx.x * 131) & (SHSZ - 1);   // decorrelate flush order
    for (int ii = threadIdx.x; ii < SHSZ; ii += 512) {
        int i = (ii + rot) & (SHSZ - 1);
        int key = skey[i];
        if (key < 0) continue;
        pl_claim(key, exists, wcnt, wl);
        float* L = mycopy + (size_t)key * 5;
        #pragma unroll
        for (int c = 0; c < 5; ++c) atomicAdd(L + c, sacc[i][c]);
    }
}

// ---------------------------------------------------------------- blur
// Iterates the compact worklist of active cells. Neighbor loads are gated by
// exists[] (missing neighbor contributes 0, matching the reference), so the
// ping-pong buffers never need zeroing. first!=0: input is the 4-copy splat
// buffer, summed on the fly.
__global__ __launch_bounds__(256)
void pl_blur(const unsigned int* __restrict__ exists,
             const int* __restrict__ wl, const int* __restrict__ wcnt,
             const float* __restrict__ in, float* __restrict__ out,
             int d0, int d1, int d2, int first) {
    int cnt = *wcnt;
    for (int i = blockIdx.x * 256 + threadIdx.x; i < cnt; i += BLURBLK * 256) {
        int didx = wl[i];
        int r  = didx & 3;
        int K0 = (((didx >> 2)  & 31) << 2) | r;
        int K1 = (((didx >> 7)  & 31) << 2) | r;
        int K2 = (((didx >> 12) & 31) << 2) | r;
        float a[5];
        size_t o = (size_t)didx * 5;
        if (first) {
            #pragma unroll
            for (int c = 0; c < 5; ++c)
                a[c] = in[o + c] + in[LATF + o + c] +
                       in[2 * LATF + o + c] + in[3 * LATF + o + c];
        } else {
            #pragma unroll
            for (int c = 0; c < 5; ++c) a[c] = in[o + c];
        }
        #pragma unroll
        for (int sgn = 0; sgn < 2; ++sgn) {
            int P0 = K0 + (sgn ? -d0 : d0);
            int P1 = K1 + (sgn ? -d1 : d1);
            int P2 = K2 + (sgn ? -d2 : d2);
            if (((unsigned)P0 < 128u) & ((unsigned)P1 < 128u) & ((unsigned)P2 < 128u)) {
                int nk = encK(P0, P1, P2);
                if (exists[nk]) {
                    size_t no = (size_t)nk * 5;
                    if (first) {
                        #pragma unroll
                        for (int c = 0; c < 5; ++c)
                            a[c] += 0.5f * (in[no + c] + in[LATF + no + c] +
                                            in[2 * LATF + no + c] + in[3 * LATF + no + c]);
                    } else {
                        #pragma unroll
                        for (int c = 0; c < 5; ++c) a[c] += 0.5f * in[no + c];
                    }
                }
            }
        }
        #pragma unroll
        for (int c = 0; c < 5; ++c) out[o + c] = a[c];
    }
}

// ---------------------------------------------------------------- slice
__global__ __launch_bounds__(256)
void pl_slice(const float* __restrict__ vg, const float* __restrict__ sg,
              const float* __restrict__ lat, float* __restrict__ out) {
    int n = blockIdx.x * 256 + threadIdx.x;
    if (n >= NPTS) return;
    int z = n >> 14;
    int y = (n >> 7) & 127;
    int x = n & 127;
    int didx[4]; float b[4];
    pl_geom(z, y, x, vg, sg, didx, b);
    float a0 = 0.f, a1 = 0.f, a2 = 0.f, a3 = 0.f, a4 = 0.f;
    #pragma unroll
    for (int r = 0; r < 4; ++r) {
        float w = b[r];
        const float* L = lat + (size_t)didx[r] * 5;
        a0 += w * L[0]; a1 += w * L[1]; a2 += w * L[2]; a3 += w * L[3]; a4 += w * L[4];
    }
    const float alpha = (float)(1.0 / 1.125);
    float norm = alpha * a4 + (float)2.220446049250313e-16;
    float invn = 1.0f / norm;
    out[n]            = (alpha * a0) * invn;
    out[NPTS + n]     = (alpha * a1) * invn;
    out[2 * NPTS + n] = (alpha * a2) * invn;
    out[3 * NPTS + n] = (alpha * a3) * invn;
}

// ---------------------------------------------------------------- launch
extern "C" void kernel_launch(void* const* d_in, const int* in_sizes, int n_in,
                              void* d_out, int out_size, void* d_ws, size_t ws_size,
                              hipStream_t stream) {
    const float* input = (const float*)d_in[0];   // (4,64,128,128)
    // d_in[1] = image: only its shape matters; unused.
    const float* vg = (const float*)d_in[2];
    const float* sg = (const float*)d_in[3];
    float* out = (float*)d_out;

    char* ws = (char*)d_ws;
    float* latc = (float*)ws;                              // 4 copies
    unsigned int* exists = (unsigned int*)(latc + (size_t)4 * LATF);
    int* wcnt = (int*)(exists + LATN);
    // ---- end of zeroed region ----
    int*   wl = (int*)(wcnt + 64);
    float* A  = (float*)(wl + LATN);
    float* B  = A + LATF;

    size_t zbytes = (size_t)4 * LATF * 4 + (size_t)LATN * 4 + 256;   // ~11 MB
    hipMemsetAsync(ws, 0, zbytes, stream);

    pl_splat<<<512, dim3(512), 0, stream>>>(input, vg, sg, latc, exists, wcnt, wl);

    // blur passes: j=0..2 -> o = ones with o[j] = -3; j=3 -> o = ones
    // ping-pong: latc(sum4) -> A -> B -> A -> B; slice reads B
    pl_blur<<<BLURBLK, dim3(256), 0, stream>>>(exists, wl, wcnt, latc, A, -3, 1, 1, 1);
    pl_blur<<<BLURBLK, dim3(256), 0, stream>>>(exists, wl, wcnt, A, B, 1, -3, 1, 0);
    pl_blur<<<BLURBLK, dim3(256), 0, stream>>>(exists, wl, wcnt, B, A, 1, 1, -3, 0);
    pl_blur<<<BLURBLK, dim3(256), 0, stream>>>(exists, wl, wcnt, A, B, 1, 1, 1, 0);

    pl_slice<<<NPTS / 256, dim3(256), 0, stream>>>(vg, sg, B, out);
}